// Round 2
// baseline (249.064 us; speedup 1.0000x reference)
//
#include <hip/hip_runtime.h>
#include <hip/hip_bf16.h>

// Isokawa quaternion layer as bf16-MFMA GEMM:
//   out[b, n*4+oc] = sigmoid( sum_k x[b,k] * C[k, n*4+oc] - theta[n*4+oc] )
// B=131072 rows, K=256, N=256. Memory floor: 134 MB in + 134 MB out = 42.6 us.
//
// R4: async streaming pipeline (T3/T4 style).
//  - x staged fp32 via global_load_lds (no VGPR result -> compiler cannot sink
//    the prefetch, unlike R3). Double buffer 2 x 64 KB, 1 block/CU, grid 256.
//  - Counted vmcnt at the barriers (8/16, never 0 in the loop): a full tile of
//    loads + the previous tile's stores stay in flight across every barrier.
//  - LDS row stride 1024 B == 0 mod banks -> 3-bit XOR swizzle on the GLOBAL
//    source (linear LDS dest, swizzled read): c16' = c16 ^ (row&7). Spreads the
//    64-lane ds_read_b128 uniformly over bank groups (128 B/cy floor).
//  - fp32->bf16 conversion moved into the K-loop (scalar casts; VALU is idle).
//  - MFMA operands swapped (breg as A) -> float4 stores; rcp-based sigmoid.

typedef __bf16 bf16_t;
typedef bf16_t bf16x8 __attribute__((ext_vector_type(8)));
typedef float f32x4 __attribute__((ext_vector_type(4)));

#define B_TOTAL 131072
#define KDIM 256
#define NDIM 256
#define ROWS 64          // batch rows per tile
#define THREADS 512      // 8 waves; wave w owns cols [w*32, w*32+32)
#define TPB 8            // tiles per block
#define GRID (B_TOTAL / (ROWS * TPB))   // 256 blocks = 1 per CU

// ---------------------------------------------------------------------------
// Kernel 1: build coefficient matrix in MFMA B-fragment order (bf16, in d_ws).
//   coef_frag[((nt*8 + ks)*64 + lane)*8 + j] = Bmat[k][col]
//     col = nt*16 + (lane&15),  k = ks*32 + (lane>>4)*8 + j
// Bmat[k][col]: col = n*4+oc, k = m*4+ic,
//   value = sign[oc][ic] * W[n, m, widx[oc][ic]]  (Hamilton, W on the left)
// ---------------------------------------------------------------------------
__global__ void coef_kernel(const float* __restrict__ W, bf16_t* __restrict__ coef) {
    const int widx[4][4] = {{0,1,2,3},{1,0,3,2},{2,3,0,1},{3,2,1,0}};
    const float sgn[4][4] = {{1.f,-1.f,-1.f,-1.f},
                             {1.f, 1.f,-1.f, 1.f},
                             {1.f, 1.f, 1.f,-1.f},
                             {1.f,-1.f, 1.f, 1.f}};
    int F = blockIdx.x * blockDim.x + threadIdx.x;   // 0..65535, one elem each
    int j    = F & 7;
    int lane = (F >> 3) & 63;
    int ks   = (F >> 9) & 7;
    int nt   = F >> 12;
    int col  = nt * 16 + (lane & 15);
    int k    = ks * 32 + (lane >> 4) * 8 + j;
    int n = col >> 2, oc = col & 3;
    int m = k >> 2,   ic = k & 3;
    coef[F] = (bf16_t)(sgn[oc][ic] * W[n * 256 + m * 4 + widx[oc][ic]]);
}

// ---------------------------------------------------------------------------
// Kernel 2: main GEMM, async double-buffered over TPB tiles.
// MFMA 16x16x32 bf16 layouts (m89/m120-verified):
//   A-op: lane holds A[m=lane&15][k=(lane>>4)*8 + j]
//   B-op: lane holds B[k=(lane>>4)*8 + j][n=lane&15]
//   C/D : col=lane&15, row=(lane>>4)*4 + reg
// D' = mfma(coefFrag, xFrag): lane&15 = batch row, quad*4+reg = 4 consecutive
// n-cols -> float4 stores (verified in R3).
// ---------------------------------------------------------------------------
__global__ __launch_bounds__(THREADS, 2)
void main_kernel(const float* __restrict__ x, const bf16x8* __restrict__ coef,
                 const float* __restrict__ theta, float* __restrict__ out) {
    __shared__ __align__(16) float xs[2][ROWS * KDIM];   // 2 x 64 KB

    const int tid  = threadIdx.x;
    const int wave = tid >> 6, lane = tid & 63;
    const int l15  = lane & 15, quad = lane >> 4;
    const long tile0 = (long)blockIdx.x * TPB;

    // --- B-fragments + theta FIRST (oldest in the vmcnt queue; done early)
    bf16x8 breg[2][8];
#pragma unroll
    for (int ct = 0; ct < 2; ct++)
#pragma unroll
        for (int ks = 0; ks < 8; ks++)
            breg[ct][ks] = coef[((wave * 2 + ct) * 8 + ks) * 64 + lane];

    f32x4 th4[2];
#pragma unroll
    for (int ct = 0; ct < 2; ct++)
        th4[ct] = *(const f32x4*)&theta[wave * 32 + ct * 16 + quad * 4];

    // --- async stage of one 64-row tile (64 KB) into xs[t&1].
    // Linear LDS slot s = i*512 + tid (16 B units); HW writes base + lane*16.
    // Source column is XOR-swizzled: slot (row, c16) holds global (row, c16^(row&7)).
    auto stage = [&](int t) {
        const float* src = x + (tile0 + t) * (long)(ROWS * KDIM);
        float* dst = &xs[t & 1][0];
#pragma unroll
        for (int i = 0; i < 8; i++) {
            int s   = i * THREADS + tid;
            int row = s >> 6;
            int c16 = (s & 63) ^ (row & 7);      // swizzled source column (16B units)
            __builtin_amdgcn_global_load_lds(
                (const __attribute__((address_space(1))) void*)(src + row * KDIM + c16 * 4),
                (__attribute__((address_space(3))) void*)(dst + (long)s * 4),
                16, 0, 0);
        }
    };

    stage(0);
    stage(1);

    const int sw = l15 & 7;                       // read-side swizzle (row&7 == l15&7)
    int rowoff[4];
#pragma unroll
    for (int rt = 0; rt < 4; rt++) rowoff[rt] = (rt * 16 + l15) * KDIM;

#pragma unroll 1
    for (int t = 0; t < TPB; t++) {
        // Wait for THIS tile's 8 loads. Younger ops that may stay in flight:
        //   t==0      : L(1)                      -> vmcnt(8)
        //   0<t<TPB-1 : S(t-1), L(t+1)            -> vmcnt(16)
        //   t==TPB-1  : S(t-1) only (no L(t+1))   -> vmcnt(8)
        if (t == 0 || t == TPB - 1)
            asm volatile("s_waitcnt vmcnt(8)" ::: "memory");
        else
            asm volatile("s_waitcnt vmcnt(16)" ::: "memory");
        __builtin_amdgcn_s_barrier();             // all waves' loads now visible

        const float* buf = &xs[t & 1][0];

        f32x4 acc[4][2];
#pragma unroll
        for (int rt = 0; rt < 4; rt++)
#pragma unroll
            for (int ct = 0; ct < 2; ct++) acc[rt][ct] = (f32x4)(0.f);

        // --- K-loop: swizzled fp32 LDS reads -> bf16 frags -> MFMA
#pragma unroll
        for (int ks = 0; ks < 8; ks++) {
            bf16x8 a[4];
#pragma unroll
            for (int rt = 0; rt < 4; rt++) {
                int cA = ((ks * 8 + quad * 2)     ^ sw) * 4;
                int cB = ((ks * 8 + quad * 2 + 1) ^ sw) * 4;
                f32x4 lo = *(const f32x4*)&buf[rowoff[rt] + cA];
                f32x4 hi = *(const f32x4*)&buf[rowoff[rt] + cB];
                bf16x8 af;
                af[0] = (bf16_t)lo[0]; af[1] = (bf16_t)lo[1];
                af[2] = (bf16_t)lo[2]; af[3] = (bf16_t)lo[3];
                af[4] = (bf16_t)hi[0]; af[5] = (bf16_t)hi[1];
                af[6] = (bf16_t)hi[2]; af[7] = (bf16_t)hi[3];
                a[rt] = af;
            }
#pragma unroll
            for (int rt = 0; rt < 4; rt++)
#pragma unroll
                for (int ct = 0; ct < 2; ct++)
                    acc[rt][ct] = __builtin_amdgcn_mfma_f32_16x16x32_bf16(
                        breg[ct][ks], a[rt], acc[rt][ct], 0, 0, 0);
        }

        // all this wave's LDS reads complete before anyone overwrites the buffer
        asm volatile("s_waitcnt lgkmcnt(0)" ::: "memory");
        __builtin_amdgcn_s_barrier();

        // --- epilogue: bias + sigmoid (fast rcp), float4 stores
        const long row0 = (tile0 + t) * ROWS;
#pragma unroll
        for (int rt = 0; rt < 4; rt++) {
            long row = row0 + rt * 16 + l15;
#pragma unroll
            for (int ct = 0; ct < 2; ct++) {
                f32x4 y;
#pragma unroll
                for (int j = 0; j < 4; j++) {
                    float s = acc[rt][ct][j] - th4[ct][j];
                    y[j] = __builtin_amdgcn_rcpf(1.0f + __expf(-s));
                }
                *(f32x4*)&out[row * NDIM + wave * 32 + ct * 16 + quad * 4] = y;
            }
        }

        // keep issue order: stores S(t) BEFORE stage(t+2) (vmcnt math above)
        asm volatile("" ::: "memory");
        if (t + 2 < TPB) stage(t + 2);
    }
}

extern "C" void kernel_launch(void* const* d_in, const int* in_sizes, int n_in,
                              void* d_out, int out_size, void* d_ws, size_t ws_size,
                              hipStream_t stream) {
    const float* x     = (const float*)d_in[0];   // (131072, 64, 4) fp32
    const float* W     = (const float*)d_in[1];   // (64, 64, 4) fp32
    const float* theta = (const float*)d_in[2];   // (64, 4) fp32
    float* out = (float*)d_out;                   // (131072, 64, 4) fp32
    bf16_t* coef = (bf16_t*)d_ws;                 // 65536 bf16 = 128 KB

    if (ws_size < 65536 * sizeof(bf16_t)) return;

    coef_kernel<<<256, 256, 0, stream>>>(W, coef);
    main_kernel<<<GRID, THREADS, 0, stream>>>(
        x, (const bf16x8*)coef, theta, out);
}